// Round 2
// baseline (531.039 us; speedup 1.0000x reference)
//
#include <hip/hip_runtime.h>

// ---------------------------------------------------------------------------
// WeightSharedBlock: B=4, N=1024, C=768, H=12, HD=64, KS=7, DFF=3072
// Strategy (round 1, correctness-first):
//   fp32 in/out; bf16 (MFMA 16x16x32) for all GEMMs; attention scores
//   materialized in bf16 in workspace; head-mixing + softmax as in-place
//   streaming kernels.
// Workspace overlaid: peak ~140 MB (attn region reused for MLP-phase bufs).
// ---------------------------------------------------------------------------

typedef unsigned short u16;
typedef __bf16 bf16x8 __attribute__((ext_vector_type(8)));
typedef float f32x4 __attribute__((ext_vector_type(4)));

using gvoid = __attribute__((address_space(1))) const void;
using lvoid = __attribute__((address_space(3))) void;
#define GLD16(GP, LP) __builtin_amdgcn_global_load_lds((gvoid*)(GP), (lvoid*)(LP), 16, 0, 0)

__device__ __forceinline__ u16 f2b(float f) {
  unsigned u = __float_as_uint(f);
  u = (u + 0x7FFFu + ((u >> 16) & 1u)) >> 16;
  return (u16)u;
}
__device__ __forceinline__ float b2f(u16 b) { return __uint_as_float(((unsigned)b) << 16); }
__device__ __forceinline__ float gelu_exact(float x) {
  return 0.5f * x * (1.f + erff(x * 0.70710678118654752f));
}

// ---------------------------------------------------------------------------
// cast fp32 -> bf16
__global__ void cast_f2b(const float* __restrict__ in, u16* __restrict__ out, int n) {
  int i = blockIdx.x * 256 + threadIdx.x;
  if (i < n) out[i] = f2b(in[i]);
}

// ---------------------------------------------------------------------------
// Row LayerNorm over 768 features. 256 threads/row, 3 elems/thread.
template <typename OutT>
__global__ __launch_bounds__(256) void ln_row(const float* __restrict__ x,
                                              const float* __restrict__ g,
                                              const float* __restrict__ be,
                                              OutT* __restrict__ out) {
  const long row = blockIdx.x;
  const float* xr = x + row * 768;
  OutT* yr = out + row * 768;
  const int tid = threadIdx.x;
  const int w = tid >> 6, lane = tid & 63;
  float v[3], s = 0.f, s2 = 0.f;
#pragma unroll
  for (int i = 0; i < 3; ++i) {
    v[i] = xr[tid + i * 256];
    s += v[i];
    s2 += v[i] * v[i];
  }
#pragma unroll
  for (int off = 32; off; off >>= 1) {
    s += __shfl_xor(s, off);
    s2 += __shfl_xor(s2, off);
  }
  __shared__ float red[8];
  if (lane == 0) { red[w] = s; red[w + 4] = s2; }
  __syncthreads();
  s = red[0] + red[1] + red[2] + red[3];
  s2 = red[4] + red[5] + red[6] + red[7];
  const float mu = s * (1.f / 768.f);
  const float var = s2 * (1.f / 768.f) - mu * mu;
  const float rstd = rsqrtf(var + 1e-5f);
#pragma unroll
  for (int i = 0; i < 3; ++i) {
    const int c = tid + i * 256;
    float y = (v[i] - mu) * rstd * g[c] + be[c];
    if constexpr (sizeof(OutT) == 2) yr[c] = f2b(y);
    else yr[c] = y;
  }
}

// ---------------------------------------------------------------------------
// bf16 GEMM: C[M,N] = act(scale * A[M,K] @ B[N,K]^T + bias) (+res)
// 128x128 tile, BK=32, 4 waves (2x2), each wave 4x4 frags of 16x16x32 MFMA.
// ZMODE 0: z unused (Z=1).  ZMODE 1: attention scores
//   (A=B=qkv buffer, z=b*12+h, q at col h*64, k at col 768+h*64).
template <int ZMODE, int ACT, bool HAS_RES, typename OutT>
__global__ __launch_bounds__(256, 2) void gemm_bt(
    const u16* __restrict__ Abase, const u16* __restrict__ Bbase, OutT* __restrict__ Cbase,
    const float* __restrict__ bias, const float* __restrict__ res,
    int M, int N, int K, int lda, int ldb, int ldc, int ldr, float scale) {
  __shared__ __align__(16) u16 As[128 * 32];
  __shared__ __align__(16) u16 Bs[128 * 32];
  const int tid = threadIdx.x;
  const int w = tid >> 6, lane = tid & 63;
  const int z = blockIdx.z;
  long aoff = 0, boff = 0, coff = 0;
  if (ZMODE == 1) {
    const int b = z / 12, h = z % 12;
    aoff = (long)b * 1024 * 2304 + h * 64;
    boff = aoff + 768;
    coff = (long)z * 1024 * 1024;
  }
  const u16* A = Abase + aoff;
  const u16* B = Bbase + boff;
  OutT* C = Cbase + coff;

  const long rowA = (long)blockIdx.y * 128;
  const long colB = (long)blockIdx.x * 128;

  f32x4 acc[4][4];
#pragma unroll
  for (int m = 0; m < 4; ++m)
#pragma unroll
    for (int n = 0; n < 4; ++n) acc[m][n] = f32x4{0.f, 0.f, 0.f, 0.f};

  const int wr = w >> 1, wc = w & 1;
  const int l16 = lane & 15, lh = lane >> 4;
  const int srow = tid >> 2;        // 0..63
  const int scol = (tid & 3) * 8;   // 0,8,16,24

  for (int k0 = 0; k0 < K; k0 += 32) {
#pragma unroll
    for (int r = 0; r < 2; ++r) {
      GLD16(A + (rowA + r * 64 + srow) * (long)lda + k0 + scol, &As[r * 2048 + w * 512]);
      GLD16(B + (colB + r * 64 + srow) * (long)ldb + k0 + scol, &Bs[r * 2048 + w * 512]);
    }
    __syncthreads();
    bf16x8 a[4], bb[4];
#pragma unroll
    for (int m = 0; m < 4; ++m)
      a[m] = *reinterpret_cast<const bf16x8*>(&As[(wr * 64 + m * 16 + l16) * 32 + lh * 8]);
#pragma unroll
    for (int n = 0; n < 4; ++n)
      bb[n] = *reinterpret_cast<const bf16x8*>(&Bs[(wc * 64 + n * 16 + l16) * 32 + lh * 8]);
#pragma unroll
    for (int m = 0; m < 4; ++m)
#pragma unroll
      for (int n = 0; n < 4; ++n)
        acc[m][n] = __builtin_amdgcn_mfma_f32_16x16x32_bf16(a[m], bb[n], acc[m][n], 0, 0, 0);
    __syncthreads();
  }

  const long row0 = rowA + wr * 64;
  const long col0 = colB + wc * 64;
#pragma unroll
  for (int m = 0; m < 4; ++m)
#pragma unroll
    for (int n = 0; n < 4; ++n)
#pragma unroll
      for (int r = 0; r < 4; ++r) {
        const long row = row0 + m * 16 + lh * 4 + r;
        const long col = col0 + n * 16 + l16;
        float v = acc[m][n][r] * scale;
        if (bias) v += bias[col];
        if (ACT == 1) v = gelu_exact(v);
        if (HAS_RES) v += res[row * (long)ldr + col];
        if constexpr (sizeof(OutT) == 2) C[row * (long)ldc + col] = f2b(v);
        else C[row * (long)ldc + col] = v;
      }
}

// ---------------------------------------------------------------------------
// In-place head mixing: attn[b,g,:,:] = sum_h T[g,h] * attn[b,h,:,:]
__global__ __launch_bounds__(256) void mix_heads(u16* __restrict__ attn,
                                                 const float* __restrict__ T) {
  __shared__ float Ts[144];
  const int tid = threadIdx.x;
  if (tid < 144) Ts[tid] = T[tid];
  __syncthreads();
  const long gid = (long)blockIdx.x * 256 + tid;
  const int b = (int)(gid >> 20);
  const long base = ((long)b * 12 << 20) | (gid & 0xFFFFF);
  float s[12];
#pragma unroll
  for (int h = 0; h < 12; ++h) s[h] = b2f(attn[base + ((long)h << 20)]);
#pragma unroll
  for (int g = 0; g < 12; ++g) {
    float o = 0.f;
#pragma unroll
    for (int h = 0; h < 12; ++h) o += Ts[g * 12 + h] * s[h];
    attn[base + ((long)g << 20)] = f2b(o);
  }
}

// ---------------------------------------------------------------------------
// In-place row softmax over 1024 entries (one block / row).
__global__ __launch_bounds__(256) void softmax_rows(u16* __restrict__ attn) {
  u16* p = attn + (long)blockIdx.x * 1024;
  const int tid = threadIdx.x;
  const int w = tid >> 6, lane = tid & 63;
  float v[4];
  float mx = -1e30f;
#pragma unroll
  for (int i = 0; i < 4; ++i) {
    v[i] = b2f(p[tid + i * 256]);
    mx = fmaxf(mx, v[i]);
  }
#pragma unroll
  for (int off = 32; off; off >>= 1) mx = fmaxf(mx, __shfl_xor(mx, off));
  __shared__ float red[8];
  if (lane == 0) red[w] = mx;
  __syncthreads();
  mx = fmaxf(fmaxf(red[0], red[1]), fmaxf(red[2], red[3]));
  float s = 0.f;
#pragma unroll
  for (int i = 0; i < 4; ++i) {
    v[i] = __expf(v[i] - mx);
    s += v[i];
  }
#pragma unroll
  for (int off = 32; off; off >>= 1) s += __shfl_xor(s, off);
  if (lane == 0) red[w + 4] = s;
  __syncthreads();
  s = red[4] + red[5] + red[6] + red[7];
  const float inv = 1.f / s;
#pragma unroll
  for (int i = 0; i < 4; ++i) p[tid + i * 256] = f2b(v[i] * inv);
}

// ---------------------------------------------------------------------------
// AV: out[b, n, h*64+d] = sum_m attn[b,h,n,m] * V[b,m,h*64+d]
// Block: 128 rows of A x 64 cols (full head dim). 4 waves, each 32x64.
__global__ __launch_bounds__(256, 2) void av_gemm(const u16* __restrict__ attn,
                                                  const u16* __restrict__ qkv,
                                                  u16* __restrict__ out) {
  __shared__ __align__(16) u16 As[128 * 32];
  __shared__ __align__(16) u16 Vt[64 * 40];  // V^T tile [d][k], padded row 40
  const int tid = threadIdx.x;
  const int w = tid >> 6, lane = tid & 63;
  const int z = blockIdx.y;
  const int b = z / 12, h = z % 12;
  const u16* A = attn + (long)z * 1024 * 1024;
  const u16* V = qkv + (long)b * 1024 * 2304 + 1536 + h * 64;
  const long rowA = (long)blockIdx.x * 128;

  f32x4 acc[2][4];
#pragma unroll
  for (int m = 0; m < 2; ++m)
#pragma unroll
    for (int n = 0; n < 4; ++n) acc[m][n] = f32x4{0.f, 0.f, 0.f, 0.f};

  const int l16 = lane & 15, lh = lane >> 4;
  const int srow = tid >> 2;
  const int scol = (tid & 3) * 8;

  for (int k0 = 0; k0 < 1024; k0 += 32) {
#pragma unroll
    for (int r = 0; r < 2; ++r)
      GLD16(A + (rowA + r * 64 + srow) * 1024 + k0 + scol, &As[r * 2048 + w * 512]);
#pragma unroll
    for (int i = 0; i < 8; ++i) {
      const int idx = i * 256 + tid;
      const int kk = idx >> 6, d = idx & 63;
      Vt[d * 40 + kk] = V[(long)(k0 + kk) * 2304 + d];
    }
    __syncthreads();
    bf16x8 a[2], bv[4];
#pragma unroll
    for (int m = 0; m < 2; ++m)
      a[m] = *reinterpret_cast<const bf16x8*>(&As[(w * 32 + m * 16 + l16) * 32 + lh * 8]);
#pragma unroll
    for (int n = 0; n < 4; ++n)
      bv[n] = *reinterpret_cast<const bf16x8*>(&Vt[(n * 16 + l16) * 40 + lh * 8]);
#pragma unroll
    for (int m = 0; m < 2; ++m)
#pragma unroll
      for (int n = 0; n < 4; ++n)
        acc[m][n] = __builtin_amdgcn_mfma_f32_16x16x32_bf16(a[m], bv[n], acc[m][n], 0, 0, 0);
    __syncthreads();
  }
  const long row0 = rowA + w * 32;
#pragma unroll
  for (int m = 0; m < 2; ++m)
#pragma unroll
    for (int n = 0; n < 4; ++n)
#pragma unroll
      for (int r = 0; r < 4; ++r) {
        const long tok = row0 + m * 16 + lh * 4 + r;
        const int d = n * 16 + l16;
        out[((long)b * 1024 + tok) * 768 + h * 64 + d] = f2b(acc[m][n][r]);
      }
}

// ---------------------------------------------------------------------------
// Depthwise conv1d over tokens, kernel 7, zero pad 3. Thread = (b,n,c).
__global__ __launch_bounds__(256) void dwconv(const float* __restrict__ h2,
                                              const float* __restrict__ wgt,
                                              const float* __restrict__ bias,
                                              float* __restrict__ ct) {
  const long gid = (long)blockIdx.x * 256 + threadIdx.x;
  const int c = (int)(gid % 768);
  const int n = (int)((gid / 768) % 1024);
  const int b = (int)(gid / (768 * 1024));
  float acc = bias[c];
#pragma unroll
  for (int t = 0; t < 7; ++t) {
    const int nn = n + t - 3;
    if (nn >= 0 && nn < 1024) acc += h2[((long)b * 1024 + nn) * 768 + c] * wgt[c * 7 + t];
  }
  ct[gid] = acc;
}

// ---------------------------------------------------------------------------
extern "C" void kernel_launch(void* const* d_in, const int* in_sizes, int n_in,
                              void* d_out, int out_size, void* d_ws, size_t ws_size,
                              hipStream_t stream) {
  const float* x      = (const float*)d_in[0];
  const float* w_qkv  = (const float*)d_in[1];
  const float* b_qkv  = (const float*)d_in[2];
  const float* w_proj = (const float*)d_in[3];
  const float* b_proj = (const float*)d_in[4];
  const float* w_fc1  = (const float*)d_in[5];
  const float* b_fc1  = (const float*)d_in[6];
  const float* w_fc2  = (const float*)d_in[7];
  const float* b_fc2  = (const float*)d_in[8];
  const float* t_bef  = (const float*)d_in[9];
  const float* t_aft  = (const float*)d_in[10];
  const float* g1     = (const float*)d_in[11];
  const float* be1    = (const float*)d_in[12];
  const float* g2     = (const float*)d_in[13];
  const float* be2    = (const float*)d_in[14];
  const float* dw_w   = (const float*)d_in[15];
  const float* dw_b   = (const float*)d_in[16];
  const float* gm     = (const float*)d_in[17];
  const float* bm     = (const float*)d_in[18];
  float* out = (float*)d_out;

  char* wsp = (char*)d_ws;
  size_t off = 0;
  auto alloc = [&](size_t bytes) {
    char* r = wsp + off;
    off += (bytes + 255) & ~(size_t)255;
    return r;
  };
  // --- persistent region ---
  u16* wqkv_b  = (u16*)alloc((size_t)2304 * 768 * 2);
  u16* wproj_b = (u16*)alloc((size_t)768 * 768 * 2);
  u16* wfc1_b  = (u16*)alloc((size_t)3072 * 768 * 2);
  u16* wfc2_b  = (u16*)alloc((size_t)768 * 3072 * 2);
  u16* h1      = (u16*)alloc((size_t)4096 * 768 * 2);   // LN1 out; dead after QKV gemm
  u16* attn_out = h1;                                   // overlay: av_gemm out (h1 dead)
  u16* qkvb    = (u16*)alloc((size_t)4096 * 2304 * 2);  // live until av_gemm
  char* attn_region = alloc((size_t)48 * 1024 * 1024 * 2);  // 100.7 MB
  u16* attn = (u16*)attn_region;                        // dead after av_gemm
  // --- overlay into attn region (dead after av_gemm): 69.3 MB < 100.7 MB ---
  size_t ro = 0;
  auto ralloc = [&](size_t bytes) {
    char* r = attn_region + ro;
    ro += (bytes + 255) & ~(size_t)255;
    return r;
  };
  float* x2   = (float*)ralloc((size_t)4096 * 768 * 4);
  float* h2   = (float*)ralloc((size_t)4096 * 768 * 4);
  float* ct   = (float*)ralloc((size_t)4096 * 768 * 4);
  u16*   hm   = (u16*)ralloc((size_t)4096 * 768 * 2);
  u16*   fc1o = (u16*)ralloc((size_t)4096 * 3072 * 2);
  (void)ws_size; (void)n_in; (void)in_sizes; (void)out_size;

  // weight casts
  cast_f2b<<<(2304 * 768 + 255) / 256, 256, 0, stream>>>(w_qkv, wqkv_b, 2304 * 768);
  cast_f2b<<<(768 * 768 + 255) / 256, 256, 0, stream>>>(w_proj, wproj_b, 768 * 768);
  cast_f2b<<<(3072 * 768 + 255) / 256, 256, 0, stream>>>(w_fc1, wfc1_b, 3072 * 768);
  cast_f2b<<<(768 * 3072 + 255) / 256, 256, 0, stream>>>(w_fc2, wfc2_b, 768 * 3072);

  // LN1
  ln_row<u16><<<4096, 256, 0, stream>>>(x, g1, be1, h1);
  // QKV GEMM: [4096,768] @ [2304,768]^T -> [4096,2304]
  gemm_bt<0, 0, false, u16><<<dim3(18, 32, 1), 256, 0, stream>>>(
      h1, wqkv_b, qkvb, b_qkv, nullptr, 4096, 2304, 768, 768, 768, 2304, 0, 1.f);
  // scores: per (b,h): q @ k^T * scale -> attn bf16
  gemm_bt<1, 0, false, u16><<<dim3(8, 8, 48), 256, 0, stream>>>(
      qkvb, qkvb, attn, nullptr, nullptr, 1024, 1024, 64, 2304, 2304, 1024, 0, 0.125f);
  // head mix before, softmax, head mix after (all in-place)
  mix_heads<<<16384, 256, 0, stream>>>(attn, t_bef);
  softmax_rows<<<48 * 1024, 256, 0, stream>>>(attn);
  mix_heads<<<16384, 256, 0, stream>>>(attn, t_aft);
  // AV
  av_gemm<<<dim3(8, 48), 256, 0, stream>>>(attn, qkvb, attn_out);
  // proj + residual -> x2 (fp32)
  gemm_bt<0, 0, true, float><<<dim3(6, 32, 1), 256, 0, stream>>>(
      attn_out, wproj_b, x2, b_proj, x, 4096, 768, 768, 768, 768, 768, 768, 1.f);
  // LN2 -> h2 fp32
  ln_row<float><<<4096, 256, 0, stream>>>(x2, g2, be2, h2);
  // depthwise conv + bias -> ct fp32
  dwconv<<<(4096 * 768) / 256, 256, 0, stream>>>(h2, dw_w, dw_b, ct);
  // LN over channels -> hm bf16
  ln_row<u16><<<4096, 256, 0, stream>>>(ct, gm, bm, hm);
  // fc1 + GELU -> fc1o bf16
  gemm_bt<0, 1, false, u16><<<dim3(24, 32, 1), 256, 0, stream>>>(
      hm, wfc1_b, fc1o, b_fc1, nullptr, 4096, 3072, 768, 768, 768, 3072, 0, 1.f);
  // fc2 + residual -> out fp32
  gemm_bt<0, 0, true, float><<<dim3(6, 32, 1), 256, 0, stream>>>(
      fc1o, wfc2_b, out, b_fc2, x2, 4096, 768, 3072, 3072, 3072, 768, 768, 1.f);
}

// Round 3
// 474.300 us; speedup vs baseline: 1.1196x; 1.1196x over previous
//
#include <hip/hip_runtime.h>

// ---------------------------------------------------------------------------
// WeightSharedBlock: B=4, N=1024, C=768, H=12, HD=64, KS=7, DFF=3072
// Round 3: dbuf GEMMs (1 barrier/K-step), fused scores+mix_before (in-register
// head mix), fused softmax+mix_after, vectorized dwconv, single cast kernel.
// ---------------------------------------------------------------------------

typedef unsigned short u16;
typedef __bf16 bf16x8 __attribute__((ext_vector_type(8)));
typedef u16 u16x8 __attribute__((ext_vector_type(8)));
typedef float f32x4 __attribute__((ext_vector_type(4)));

using gvoid = __attribute__((address_space(1))) const void;
using lvoid = __attribute__((address_space(3))) void;
#define GLD16(GP, LP) __builtin_amdgcn_global_load_lds((gvoid*)(GP), (lvoid*)(LP), 16, 0, 0)

__device__ __forceinline__ u16 f2b(float f) {
  unsigned u = __float_as_uint(f);
  u = (u + 0x7FFFu + ((u >> 16) & 1u)) >> 16;
  return (u16)u;
}
__device__ __forceinline__ float b2f(u16 b) { return __uint_as_float(((unsigned)b) << 16); }
__device__ __forceinline__ float gelu_exact(float x) {
  return 0.5f * x * (1.f + erff(x * 0.70710678118654752f));
}

// ---------------------------------------------------------------------------
// single combined weight cast (4 segments, float4 -> 4x bf16)
__global__ __launch_bounds__(256) void cast_all(const float* __restrict__ s0,
                                                const float* __restrict__ s1,
                                                const float* __restrict__ s2,
                                                const float* __restrict__ s3,
                                                u16* __restrict__ d0, u16* __restrict__ d1,
                                                u16* __restrict__ d2, u16* __restrict__ d3) {
  const int n0 = 1769472 / 4, n1 = 589824 / 4, n2 = 2359296 / 4;
  int j = blockIdx.x * 256 + threadIdx.x;
  const float* src;
  u16* dst;
  if (j < n0) { src = s0; dst = d0; }
  else if ((j -= n0) < n1) { src = s1; dst = d1; }
  else if ((j -= n1) < n2) { src = s2; dst = d2; }
  else { j -= n2; src = s3; dst = d3; }
  const float4 v = ((const float4*)src)[j];
  ushort4 o;
  o.x = f2b(v.x); o.y = f2b(v.y); o.z = f2b(v.z); o.w = f2b(v.w);
  ((ushort4*)dst)[j] = o;
}

// ---------------------------------------------------------------------------
// Row LayerNorm over 768 features. 256 threads/row, 3 elems/thread.
template <typename OutT>
__global__ __launch_bounds__(256) void ln_row(const float* __restrict__ x,
                                              const float* __restrict__ g,
                                              const float* __restrict__ be,
                                              OutT* __restrict__ out) {
  const long row = blockIdx.x;
  const float* xr = x + row * 768;
  OutT* yr = out + row * 768;
  const int tid = threadIdx.x;
  const int w = tid >> 6, lane = tid & 63;
  float v[3], s = 0.f, s2 = 0.f;
#pragma unroll
  for (int i = 0; i < 3; ++i) {
    v[i] = xr[tid + i * 256];
    s += v[i];
    s2 += v[i] * v[i];
  }
#pragma unroll
  for (int off = 32; off; off >>= 1) {
    s += __shfl_xor(s, off);
    s2 += __shfl_xor(s2, off);
  }
  __shared__ float red[8];
  if (lane == 0) { red[w] = s; red[w + 4] = s2; }
  __syncthreads();
  s = red[0] + red[1] + red[2] + red[3];
  s2 = red[4] + red[5] + red[6] + red[7];
  const float mu = s * (1.f / 768.f);
  const float var = s2 * (1.f / 768.f) - mu * mu;
  const float rstd = rsqrtf(var + 1e-5f);
#pragma unroll
  for (int i = 0; i < 3; ++i) {
    const int c = tid + i * 256;
    float y = (v[i] - mu) * rstd * g[c] + be[c];
    if constexpr (sizeof(OutT) == 2) yr[c] = f2b(y);
    else yr[c] = y;
  }
}

// ---------------------------------------------------------------------------
// bf16 GEMM: C[M,N] = act(A[M,K] @ B[N,K]^T + bias) (+res)
// TMxTN tile, BK=32, 4 waves (2x2 quadrants), double-buffered LDS,
// ONE barrier per K-step (stage next-tile before compute of current).
// XOR-swizzled staging: source-slot s^(row&3), read xor lh^(l16&3).
template <int TM, int TN, int ACT, bool HAS_RES, typename OutT>
__global__ __launch_bounds__(256) void gemm_bt(
    const u16* __restrict__ A, const u16* __restrict__ B, OutT* __restrict__ C,
    const float* __restrict__ bias, const float* __restrict__ res,
    int K, int lda, int ldb, int ldc, int ldr) {
  constexpr int WM = TM / 2, WN = TN / 2, MR = WM / 16, NR = WN / 16;
  __shared__ __align__(16) u16 As[2][TM * 32];
  __shared__ __align__(16) u16 Bs[2][TN * 32];
  const int tid = threadIdx.x;
  const int w = tid >> 6, lane = tid & 63;
  const int wr = w >> 1, wc = w & 1;
  const int l16 = lane & 15, lh = lane >> 4;
  const long rowA = (long)blockIdx.y * TM;
  const long colB = (long)blockIdx.x * TN;
  const int srow = tid >> 2;
  const int scol = (((tid & 3) ^ (srow & 3))) * 8;

  f32x4 acc[MR][NR];
#pragma unroll
  for (int m = 0; m < MR; ++m)
#pragma unroll
    for (int n = 0; n < NR; ++n) acc[m][n] = f32x4{0.f, 0.f, 0.f, 0.f};

  auto stage = [&](int buf, int k0) {
#pragma unroll
    for (int r = 0; r < TM / 64; ++r)
      GLD16(A + (rowA + r * 64 + srow) * (long)lda + k0 + scol, (char*)As[buf] + r * 4096 + w * 1024);
#pragma unroll
    for (int r = 0; r < TN / 64; ++r)
      GLD16(B + (colB + r * 64 + srow) * (long)ldb + k0 + scol, (char*)Bs[buf] + r * 4096 + w * 1024);
  };

  stage(0, 0);
  __syncthreads();
  const int nk = K >> 5;
  const int rx = (lh ^ (l16 & 3)) * 8;
  for (int t = 0; t < nk; ++t) {
    const int buf = t & 1;
    if (t + 1 < nk) stage(buf ^ 1, (t + 1) << 5);
    bf16x8 a[MR], bb[NR];
#pragma unroll
    for (int m = 0; m < MR; ++m)
      a[m] = *(const bf16x8*)&As[buf][(wr * WM + m * 16 + l16) * 32 + rx];
#pragma unroll
    for (int n = 0; n < NR; ++n)
      bb[n] = *(const bf16x8*)&Bs[buf][(wc * WN + n * 16 + l16) * 32 + rx];
#pragma unroll
    for (int m = 0; m < MR; ++m)
#pragma unroll
      for (int n = 0; n < NR; ++n)
        acc[m][n] = __builtin_amdgcn_mfma_f32_16x16x32_bf16(a[m], bb[n], acc[m][n], 0, 0, 0);
    __syncthreads();
  }

  const long row0 = rowA + wr * WM;
  const long col0 = colB + wc * WN;
#pragma unroll
  for (int m = 0; m < MR; ++m)
#pragma unroll
    for (int n = 0; n < NR; ++n)
#pragma unroll
      for (int r = 0; r < 4; ++r) {
        const long row = row0 + m * 16 + lh * 4 + r;
        const long col = col0 + n * 16 + l16;
        float v = acc[m][n][r];
        if (bias) v += bias[col];
        if (ACT == 1) v = gelu_exact(v);
        if (HAS_RES) v += res[row * (long)ldr + col];
        if constexpr (sizeof(OutT) == 2) C[row * (long)ldc + col] = f2b(v);
        else C[row * (long)ldc + col] = v;
      }
}

// ---------------------------------------------------------------------------
// Fused scores + head-mix-before: block = (b, 32x32 (n,m) tile), 4 waves in
// 16x16 quadrants; each wave computes ALL 12 heads for its quadrant, so the
// head mix is purely in-register. Writes mixed scores (bf16) to attn.
__global__ __launch_bounds__(256) void scores_mix(const u16* __restrict__ qkv,
                                                  const float* __restrict__ Tb,
                                                  u16* __restrict__ attn) {
  __shared__ __align__(16) u16 Qs[32 * 768];
  __shared__ __align__(16) u16 Ks[32 * 768];
  __shared__ float Ts[144];
  const int tid = threadIdx.x;
  const int w = tid >> 6, lane = tid & 63;
  const int b = blockIdx.z;
  const int n0 = blockIdx.y * 32, m0 = blockIdx.x * 32;
  if (tid < 144) Ts[tid] = Tb[tid];
  const char* qb = (const char*)qkv;
  // stage Q,K: linear LDS dest, XOR-swizzled (within-row 16B slot) source
#pragma unroll
  for (int i = 0; i < 12; ++i) {
    const int idx = i * 256 + tid;
    const int r = idx / 96, t = idx % 96;
    const int s = t ^ (r & 7);
    const long rQ = ((long)b * 1024 + n0 + r) * 4608;
    const long rK = ((long)b * 1024 + m0 + r) * 4608;
    GLD16(qb + rQ + s * 16, (char*)Qs + (i * 256 + w * 64) * 16);
    GLD16(qb + rK + 1536 + s * 16, (char*)Ks + (i * 256 + w * 64) * 16);
  }
  __syncthreads();
  const int wr = w >> 1, wc = w & 1;
  const int l16 = lane & 15, lh = lane >> 4;
  const int x7 = l16 & 7;
  const char* Qrow = (const char*)Qs + (wr * 16 + l16) * 1536;
  const char* Krow = (const char*)Ks + (wc * 16 + l16) * 1536;
  f32x4 acc[12];
#pragma unroll
  for (int h = 0; h < 12; ++h) acc[h] = f32x4{0.f, 0.f, 0.f, 0.f};
#pragma unroll
  for (int h = 0; h < 12; ++h)
#pragma unroll
    for (int kk = 0; kk < 2; ++kk) {
      const int slot = h * 8 + kk * 4 + lh;
      const bf16x8 a = *(const bf16x8*)(Qrow + (slot ^ x7) * 16);
      const bf16x8 bb = *(const bf16x8*)(Krow + (slot ^ x7) * 16);
      acc[h] = __builtin_amdgcn_mfma_f32_16x16x32_bf16(a, bb, acc[h], 0, 0, 0);
    }
  // in-register head mix + write
#pragma unroll
  for (int g = 0; g < 12; ++g) {
    f32x4 o = f32x4{0.f, 0.f, 0.f, 0.f};
#pragma unroll
    for (int h = 0; h < 12; ++h) o += Ts[g * 12 + h] * acc[h];
    u16* dst = attn + (((long)(b * 12 + g)) << 20) +
               (long)(n0 + wr * 16 + lh * 4) * 1024 + (m0 + wc * 16 + l16);
#pragma unroll
    for (int r = 0; r < 4; ++r) dst[r * 1024] = f2b(o[r] * 0.125f);
  }
}

// ---------------------------------------------------------------------------
// Fused softmax + head-mix-after: block = (b, n) row; all 12 head-rows live
// in registers (p[12][4] per thread); 12x12 mix in-register; in-place update.
__global__ __launch_bounds__(256) void softmax_mix(u16* __restrict__ attn,
                                                   const float* __restrict__ Tg) {
  const int bi = blockIdx.x >> 10;
  const int n = blockIdx.x & 1023;
  __shared__ float Ta[144];
  __shared__ float red[8];
  const int tid = threadIdx.x;
  const int w = tid >> 6, lane = tid & 63;
  if (tid < 144) Ta[tid] = Tg[tid];
  const long base = (((long)bi * 12) << 20) + (long)n * 1024;
  float p[12][4];
#pragma unroll
  for (int h = 0; h < 12; ++h) {
    const uint2 d = ((const uint2*)(attn + base + ((long)h << 20)))[tid];
    float v[4] = {b2f((u16)(d.x & 0xffff)), b2f((u16)(d.x >> 16)),
                  b2f((u16)(d.y & 0xffff)), b2f((u16)(d.y >> 16))};
    float mx = fmaxf(fmaxf(v[0], v[1]), fmaxf(v[2], v[3]));
#pragma unroll
    for (int off = 32; off; off >>= 1) mx = fmaxf(mx, __shfl_xor(mx, off));
    __syncthreads();  // protect red[] reuse across h iterations
    if (lane == 0) red[w] = mx;
    __syncthreads();
    mx = fmaxf(fmaxf(red[0], red[1]), fmaxf(red[2], red[3]));
    float s = 0.f;
#pragma unroll
    for (int i = 0; i < 4; ++i) {
      v[i] = __expf(v[i] - mx);
      s += v[i];
    }
#pragma unroll
    for (int off = 32; off; off >>= 1) s += __shfl_xor(s, off);
    if (lane == 0) red[w + 4] = s;
    __syncthreads();
    s = red[4] + red[5] + red[6] + red[7];
    const float inv = 1.f / s;
#pragma unroll
    for (int i = 0; i < 4; ++i) p[h][i] = v[i] * inv;
  }
#pragma unroll
  for (int g = 0; g < 12; ++g) {
    float o[4] = {0.f, 0.f, 0.f, 0.f};
#pragma unroll
    for (int h = 0; h < 12; ++h) {
      const float t = Ta[g * 12 + h];
#pragma unroll
      for (int i = 0; i < 4; ++i) o[i] += t * p[h][i];
    }
    uint2 d;
    d.x = (unsigned)f2b(o[0]) | ((unsigned)f2b(o[1]) << 16);
    d.y = (unsigned)f2b(o[2]) | ((unsigned)f2b(o[3]) << 16);
    ((uint2*)(attn + base + ((long)g << 20)))[tid] = d;
  }
}

// ---------------------------------------------------------------------------
// AV: out[b,n,h*64+d] = sum_m attn[b,h,n,m] * V[b,m,h*64+d]
// 64-row tiles, 4 waves (16 rows each), double-buffered, V transposed in-reg
// (8 scalar loads -> one b128 LDS write per wave).
__global__ __launch_bounds__(256) void av_gemm(const u16* __restrict__ attn,
                                               const u16* __restrict__ qkv,
                                               u16* __restrict__ out) {
  __shared__ __align__(16) u16 As[2][64 * 32];
  __shared__ __align__(16) u16 Vt[2][64 * 40];
  const int tid = threadIdx.x;
  const int w = tid >> 6, lane = tid & 63;
  const int z = blockIdx.y, b = z / 12, h = z % 12;
  const u16* A = attn + ((long)z << 20);
  const u16* V = qkv + (long)b * 1024 * 2304 + 1536 + h * 64;
  const int rowA = blockIdx.x * 64;
  const int srow = tid >> 2;
  const int scol = (((tid & 3) ^ (srow & 3))) * 8;
  const int l16 = lane & 15, lh = lane >> 4;

  f32x4 acc[4];
#pragma unroll
  for (int n = 0; n < 4; ++n) acc[n] = f32x4{0.f, 0.f, 0.f, 0.f};

  auto stageA = [&](int buf, int k0) {
    GLD16(A + (long)(rowA + srow) * 1024 + k0 + scol, (char*)As[buf] + w * 1024);
  };
  auto stageV = [&](int buf, int k0) {
    u16x8 tmp;
#pragma unroll
    for (int j = 0; j < 8; ++j) tmp[j] = V[(long)(k0 + w * 8 + j) * 2304 + lane];
    *(u16x8*)&Vt[buf][lane * 40 + w * 8] = tmp;
  };

  stageA(0, 0);
  stageV(0, 0);
  __syncthreads();
  for (int t = 0; t < 32; ++t) {
    const int buf = t & 1;
    if (t < 31) { stageA(buf ^ 1, (t + 1) * 32); stageV(buf ^ 1, (t + 1) * 32); }
    const bf16x8 a = *(const bf16x8*)&As[buf][(w * 16 + l16) * 32 + (lh ^ (l16 & 3)) * 8];
    bf16x8 bv[4];
#pragma unroll
    for (int n = 0; n < 4; ++n)
      bv[n] = *(const bf16x8*)&Vt[buf][(n * 16 + l16) * 40 + lh * 8];
#pragma unroll
    for (int n = 0; n < 4; ++n)
      acc[n] = __builtin_amdgcn_mfma_f32_16x16x32_bf16(a, bv[n], acc[n], 0, 0, 0);
    __syncthreads();
  }
  const int row0 = rowA + w * 16 + lh * 4;
#pragma unroll
  for (int n = 0; n < 4; ++n)
#pragma unroll
    for (int r = 0; r < 4; ++r)
      out[((long)b * 1024 + row0 + r) * 768 + h * 64 + n * 16 + l16] = f2b(acc[n][r]);
}

// ---------------------------------------------------------------------------
// Depthwise conv1d over tokens, kernel 7, zero pad 3, float4 over channels.
__global__ __launch_bounds__(256) void dwconv4(const float* __restrict__ h2,
                                               const float* __restrict__ wgt,
                                               const float* __restrict__ bias,
                                               float* __restrict__ ct) {
  const int idx = blockIdx.x * 256 + threadIdx.x;  // 4*1024*192
  const int c4 = idx % 192;
  const int n = (idx / 192) % 1024;
  const int b = idx / (192 * 1024);
  const int c = c4 * 4;
  float4 acc = ((const float4*)bias)[c4];
#pragma unroll
  for (int t = 0; t < 7; ++t) {
    const int nn = n + t - 3;
    if (nn >= 0 && nn < 1024) {
      const float4 v = *(const float4*)&h2[((long)(b << 10) + nn) * 768 + c];
      acc.x += v.x * wgt[(c + 0) * 7 + t];
      acc.y += v.y * wgt[(c + 1) * 7 + t];
      acc.z += v.z * wgt[(c + 2) * 7 + t];
      acc.w += v.w * wgt[(c + 3) * 7 + t];
    }
  }
  ((float4*)ct)[idx] = acc;
}

// ---------------------------------------------------------------------------
extern "C" void kernel_launch(void* const* d_in, const int* in_sizes, int n_in,
                              void* d_out, int out_size, void* d_ws, size_t ws_size,
                              hipStream_t stream) {
  const float* x      = (const float*)d_in[0];
  const float* w_qkv  = (const float*)d_in[1];
  const float* b_qkv  = (const float*)d_in[2];
  const float* w_proj = (const float*)d_in[3];
  const float* b_proj = (const float*)d_in[4];
  const float* w_fc1  = (const float*)d_in[5];
  const float* b_fc1  = (const float*)d_in[6];
  const float* w_fc2  = (const float*)d_in[7];
  const float* b_fc2  = (const float*)d_in[8];
  const float* t_bef  = (const float*)d_in[9];
  const float* t_aft  = (const float*)d_in[10];
  const float* g1     = (const float*)d_in[11];
  const float* be1    = (const float*)d_in[12];
  const float* g2     = (const float*)d_in[13];
  const float* be2    = (const float*)d_in[14];
  const float* dw_w   = (const float*)d_in[15];
  const float* dw_b   = (const float*)d_in[16];
  const float* gm     = (const float*)d_in[17];
  const float* bm     = (const float*)d_in[18];
  float* out = (float*)d_out;

  char* wsp = (char*)d_ws;
  size_t off = 0;
  auto alloc = [&](size_t bytes) {
    char* r = wsp + off;
    off += (bytes + 255) & ~(size_t)255;
    return r;
  };
  u16* wqkv_b  = (u16*)alloc((size_t)2304 * 768 * 2);
  u16* wproj_b = (u16*)alloc((size_t)768 * 768 * 2);
  u16* wfc1_b  = (u16*)alloc((size_t)3072 * 768 * 2);
  u16* wfc2_b  = (u16*)alloc((size_t)768 * 3072 * 2);
  u16* h1      = (u16*)alloc((size_t)4096 * 768 * 2);   // LN1 out; dead after QKV
  u16* attn_out = h1;                                   // overlay
  u16* qkvb    = (u16*)alloc((size_t)4096 * 2304 * 2);
  char* attn_region = alloc((size_t)48 * 1024 * 1024 * 2);
  u16* attn = (u16*)attn_region;                        // dead after av_gemm
  size_t ro = 0;
  auto ralloc = [&](size_t bytes) {
    char* r = attn_region + ro;
    ro += (bytes + 255) & ~(size_t)255;
    return r;
  };
  float* x2   = (float*)ralloc((size_t)4096 * 768 * 4);
  float* h2   = (float*)ralloc((size_t)4096 * 768 * 4);
  float* ct   = (float*)ralloc((size_t)4096 * 768 * 4);
  u16*   hm   = (u16*)ralloc((size_t)4096 * 768 * 2);
  u16*   fc1o = (u16*)ralloc((size_t)4096 * 3072 * 2);
  (void)ws_size; (void)n_in; (void)in_sizes; (void)out_size;

  // weight casts (one kernel)
  cast_all<<<6912, 256, 0, stream>>>(w_qkv, w_proj, w_fc1, w_fc2,
                                     wqkv_b, wproj_b, wfc1_b, wfc2_b);
  // LN1
  ln_row<u16><<<4096, 256, 0, stream>>>(x, g1, be1, h1);
  // QKV: [4096,768] @ [2304,768]^T -> [4096,2304]
  gemm_bt<128, 64, 0, false, u16><<<dim3(36, 32), 256, 0, stream>>>(
      h1, wqkv_b, qkvb, b_qkv, nullptr, 768, 768, 768, 2304, 0);
  // fused scores + mix_before -> attn (mixed, scaled)
  scores_mix<<<dim3(32, 32, 4), 256, 0, stream>>>(qkvb, t_bef, attn);
  // fused softmax + mix_after (in-place)
  softmax_mix<<<4096, 256, 0, stream>>>(attn, t_aft);
  // AV
  av_gemm<<<dim3(16, 48), 256, 0, stream>>>(attn, qkvb, attn_out);
  // proj + residual -> x2 (fp32)
  gemm_bt<64, 64, 0, true, float><<<dim3(12, 64), 256, 0, stream>>>(
      attn_out, wproj_b, x2, b_proj, x, 768, 768, 768, 768, 768);
  // LN2 -> h2
  ln_row<float><<<4096, 256, 0, stream>>>(x2, g2, be2, h2);
  // depthwise conv + bias -> ct
  dwconv4<<<3072, 256, 0, stream>>>(h2, dw_w, dw_b, ct);
  // LN mid -> hm (bf16)
  ln_row<u16><<<4096, 256, 0, stream>>>(ct, gm, bm, hm);
  // fc1 + GELU -> fc1o
  gemm_bt<128, 64, 1, false, u16><<<dim3(48, 32), 256, 0, stream>>>(
      hm, wfc1_b, fc1o, b_fc1, nullptr, 768, 768, 768, 3072, 0);
  // fc2 + residual -> out
  gemm_bt<64, 64, 0, true, float><<<dim3(12, 64), 256, 0, stream>>>(
      fc1o, wfc2_b, out, b_fc2, x2, 3072, 3072, 3072, 768, 768);
}